// Round 5
// baseline (63.835 us; speedup 1.0000x reference)
//
#include <hip/hip_runtime.h>
#include <hip/hip_bf16.h>

#define NS     256
#define FEAT   8192
#define BD     128
#define CD     16
#define NOUT   2048
#define OUTW   8320              // FEAT + BD
#define KSPLIT 16
#define KC     (FEAT / KSPLIT)   // 512
#define BK     32
#define NSTEP  (KC / BK)         // 16
#define BM     256
#define BN     128

typedef float f32x4 __attribute__((ext_vector_type(4)));
typedef short bf16x8 __attribute__((ext_vector_type(8)));
typedef short bf16x4 __attribute__((ext_vector_type(4)));

typedef unsigned int u32;
typedef __attribute__((address_space(3))) u32 lds_u32;
typedef const __attribute__((address_space(1))) u32 gbl_u32;

// direct global->LDS, 16 B per lane; LDS dest = wave-uniform base + lane*16.
__device__ __forceinline__ void gl_lds16(const void* g, void* l) {
    __builtin_amdgcn_global_load_lds((gbl_u32*)g, (lds_u32*)l, 16, 0, 0);
}

__device__ __forceinline__ bf16x4 cvt4(float a, float b, float c, float d) {
    union { __hip_bfloat162 h[2]; bf16x4 s; } u;
    u.h[0] = __float22bfloat162_rn(float2{a, b});
    u.h[1] = __float22bfloat162_rn(float2{c, d});
    return u.s;
}

__device__ __forceinline__ f32x4 bf4_to_f32(bf16x4 s) {
    f32x4 r;
    r.x = __uint_as_float(((u32)(unsigned short)s.x) << 16);
    r.y = __uint_as_float(((u32)(unsigned short)s.y) << 16);
    r.z = __uint_as_float(((u32)(unsigned short)s.z) << 16);
    r.w = __uint_as_float(((u32)(unsigned short)s.w) << 16);
    return r;
}

// -------------------------------- copy inp -> out, zero o-cols, produce Abf -
__global__ __launch_bounds__(256) void mbd_copy_kernel(const float* __restrict__ in,
                                                       float* __restrict__ out,
                                                       short* __restrict__ Abf) {
    int row = blockIdx.y;
    int c4  = blockIdx.x * 256 + threadIdx.x;   // f32x4 index within out row
    if (c4 < 2048) {
        f32x4 v = *(const f32x4*)(in + (size_t)row * FEAT + c4 * 4);
        *(f32x4*)(out + (size_t)row * OUTW + c4 * 4) = v;
        *(bf16x4*)(Abf + (size_t)row * FEAT + c4 * 4) = cvt4(v.x, v.y, v.z, v.w);
    } else if (c4 < 2080) {
        *(f32x4*)(out + (size_t)row * OUTW + c4 * 4) = (f32x4){0.f, 0.f, 0.f, 0.f};
    }
}

// ---------------------------------------------------------------- GEMM ------
// Mt_part[kc][col][row] (bf16) = (Abf[:, kc-slice] @ T[kc-slice, :])^T.
// BM=256 (whole M per block) -> T read exactly once from HBM.
// A staged bf16 [m][k] (64-B rows, m97 self-conflict-free banking),
// B staged f32 [k][n] (untransposed, linear) - both via global_load_lds x16.
// B-frags: 8 strided ds_read_b32 + cvt per frag (transpose on read side).
__global__ __launch_bounds__(512, 2) void mbd_gemm_kernel(const short* __restrict__ Abf,
                                                          const float* __restrict__ T,
                                                          short* __restrict__ Mt) {
    __shared__ short Als[2][BM * BK];   // 2 x 16 KB (bf16 [m][k])
    __shared__ float Bls[2][BK * BN];   // 2 x 16 KB (f32  [k][n])

    const int tid = threadIdx.x, lane = tid & 63, l15 = lane & 15, w = tid >> 6;
    const int wm = (w & 3) * 64, wn = (w >> 2) * 64;   // wave tile 64x64

    const int kc = blockIdx.x & 15;          // round-robin: XCD x gets kc {x, x+8}
    const int n0 = (blockIdx.x >> 4) * BN;
    const int kbase = kc * KC;

    // staging sources: chunk (w*2+u) of 1024 B; HW scatters lane*16 within it
    const short* ag[2];
    const float* bg[2];
#pragma unroll
    for (int u = 0; u < 2; ++u) {
        int arow = (w * 2 + u) * 16 + (lane >> 2);          // 0..255
        ag[u] = Abf + (size_t)arow * FEAT + kbase + (lane & 3) * 8;
        int krow = (w * 2 + u) * 2 + (lane >> 5);           // 0..31
        bg[u] = T + (size_t)(kbase + krow) * NOUT + n0 + (lane & 31) * 4;
    }

    const int kof = (lane >> 4) * 8;
    int aro[4], bco[4];
#pragma unroll
    for (int m = 0; m < 4; ++m) aro[m] = (wm + m * 16 + l15) * BK + kof;
#pragma unroll
    for (int n = 0; n < 4; ++n) bco[n] = wn + n * 16 + l15;

    f32x4 acc[4][4];
#pragma unroll
    for (int m = 0; m < 4; ++m)
#pragma unroll
        for (int n = 0; n < 4; ++n) acc[m][n] = (f32x4){0.f, 0.f, 0.f, 0.f};

    // prologue: stage tile 0 into buf 0
#pragma unroll
    for (int u = 0; u < 2; ++u) gl_lds16(ag[u], &Als[0][(w * 2 + u) * 512]);
#pragma unroll
    for (int u = 0; u < 2; ++u) gl_lds16(bg[u], &Bls[0][(w * 2 + u) * 256]);
    __syncthreads();   // barrier auto-drains vmcnt for global_load_lds

    for (int kt = 0; kt < NSTEP; ++kt) {
        const int cur = kt & 1;
        if (kt + 1 < NSTEP) {   // stage next tile into other buffer
#pragma unroll
            for (int u = 0; u < 2; ++u)
                gl_lds16(ag[u] + (kt + 1) * BK, &Als[cur ^ 1][(w * 2 + u) * 512]);
#pragma unroll
            for (int u = 0; u < 2; ++u)
                gl_lds16(bg[u] + (size_t)(kt + 1) * BK * NOUT,
                         &Bls[cur ^ 1][(w * 2 + u) * 256]);
        }
        // fragments
        bf16x8 af[4], bf[4];
#pragma unroll
        for (int m = 0; m < 4; ++m) af[m] = *(const bf16x8*)&Als[cur][aro[m]];
#pragma unroll
        for (int n = 0; n < 4; ++n) {
            float f0 = Bls[cur][(kof + 0) * BN + bco[n]];
            float f1 = Bls[cur][(kof + 1) * BN + bco[n]];
            float f2 = Bls[cur][(kof + 2) * BN + bco[n]];
            float f3 = Bls[cur][(kof + 3) * BN + bco[n]];
            float f4 = Bls[cur][(kof + 4) * BN + bco[n]];
            float f5 = Bls[cur][(kof + 5) * BN + bco[n]];
            float f6 = Bls[cur][(kof + 6) * BN + bco[n]];
            float f7 = Bls[cur][(kof + 7) * BN + bco[n]];
            bf16x4 lo = cvt4(f0, f1, f2, f3), hi = cvt4(f4, f5, f6, f7);
            bf16x8 t;
            t[0] = lo.x; t[1] = lo.y; t[2] = lo.z; t[3] = lo.w;
            t[4] = hi.x; t[5] = hi.y; t[6] = hi.z; t[7] = hi.w;
            bf[n] = t;
        }
        __builtin_amdgcn_s_setprio(1);
#pragma unroll
        for (int m = 0; m < 4; ++m)
#pragma unroll
            for (int n = 0; n < 4; ++n)
                acc[m][n] = __builtin_amdgcn_mfma_f32_16x16x32_bf16(
                    af[m], bf[n], acc[m][n], 0, 0, 0);
        __builtin_amdgcn_s_setprio(0);
        __syncthreads();   // drains this step's global_load_lds before reuse
    }

    // epilogue: C/D layout col = l&15, row = (l>>4)*4 + r  [m89-verified]
    short* Mp = Mt + (size_t)kc * NOUT * NS;
    const int r0 = (lane >> 4) * 4;
#pragma unroll
    for (int m = 0; m < 4; ++m)
#pragma unroll
        for (int n = 0; n < 4; ++n) {
            int col = n0 + wn + n * 16 + l15;
            int row = wm + m * 16 + r0;
            *(bf16x4*)&Mp[(size_t)col * NS + row] =
                cvt4(acc[m][n].x, acc[m][n].y, acc[m][n].z, acc[m][n].w);
        }
}

// ---------------------------------------------------------------- pairwise --
// block (b, jhalf): o_part[i,b] = sum_{j in half} exp(-sum_c |M[i,c]-M[j,c]|)
// Mt bf16 layout [p][col][row]; fold reads fully coalesced.
__global__ __launch_bounds__(256) void mbd_pair_kernel(const short* __restrict__ Mt,
                                                       float* __restrict__ out) {
    const int b = blockIdx.x >> 1, jh = blockIdx.x & 1;
    const int t = threadIdx.x;
    __shared__ float ldsT[CD][NS];       // [c][row] 16 KB
    __shared__ float rows[NS][20];       // [row][c] padded (80 B pitch) 20 KB

#pragma unroll
    for (int u4 = 0; u4 < 4; ++u4) {
        int u = t + u4 * 256;
        int c = u >> 6, r4 = (u & 63) * 4;
        f32x4 v = (f32x4){0.f, 0.f, 0.f, 0.f};
#pragma unroll
        for (int p = 0; p < KSPLIT; ++p)
            v += bf4_to_f32(*(const bf16x4*)(Mt +
                     ((size_t)p * NOUT + (size_t)b * CD + c) * NS + r4));
        *(f32x4*)&ldsT[c][r4] = v;
    }
    __syncthreads();

    float my[16];
#pragma unroll
    for (int c = 0; c < 16; ++c) my[c] = ldsT[c][t];   // contiguous -> conflict-free
#pragma unroll
    for (int c = 0; c < 16; ++c) rows[t][c] = my[c];
    __syncthreads();

    float o0 = 0.f, o1 = 0.f;
    const int jbase = jh * 128;
    for (int jj = 0; jj < 128; jj += 2) {
#pragma unroll
        for (int s = 0; s < 2; ++s) {
            const float* rp = &rows[jbase + jj + s][0];   // uniform -> broadcast
            float d0 = 0.f, d1 = 0.f, d2 = 0.f, d3 = 0.f;
#pragma unroll
            for (int q = 0; q < 4; ++q) {
                f32x4 r = *(const f32x4*)(rp + q * 4);
                d0 += fabsf(my[q * 4 + 0] - r.x);
                d1 += fabsf(my[q * 4 + 1] - r.y);
                d2 += fabsf(my[q * 4 + 2] - r.z);
                d3 += fabsf(my[q * 4 + 3] - r.w);
            }
            float d = (d0 + d1) + (d2 + d3);
            if (s == 0) o0 += __expf(-d); else o1 += __expf(-d);
        }
    }
    // exactly two addends per address -> f32 add commutative -> deterministic
    atomicAdd(&out[(size_t)t * OUTW + FEAT + b], o0 + o1);
}

// ---------------------------------------------------------------- launch ----
extern "C" void kernel_launch(void* const* d_in, const int* in_sizes, int n_in,
                              void* d_out, int out_size, void* d_ws, size_t ws_size,
                              hipStream_t stream) {
    const float* inp = (const float*)d_in[0];
    const float* T   = (const float*)d_in[1];
    float* out = (float*)d_out;

    // ws layout: Abf bf16 [256][8192] = 4 MiB, then Mt bf16 [16][2048][256] = 16 MiB.
    // (R3/R4 ran the 32-MiB split path, so ws_size >= 32 MiB on this harness.)
    short* Abf = (short*)d_ws;
    short* Mt  = Abf + (size_t)NS * FEAT;

    mbd_copy_kernel<<<dim3(9, 256), 256, 0, stream>>>(inp, out, Abf);
    mbd_gemm_kernel<<<256, 512, 0, stream>>>(Abf, T, Mt);
    mbd_pair_kernel<<<BD * 2, 256, 0, stream>>>(Mt, out);
}

// Round 6
// 57.547 us; speedup vs baseline: 1.1093x; 1.1093x over previous
//
#include <hip/hip_runtime.h>
#include <hip/hip_bf16.h>

#define NS     256
#define FEAT   8192
#define BD     128
#define CD     16
#define NOUT   2048
#define OUTW   8320              // FEAT + BD
#define KSPLIT 16
#define KC     (FEAT / KSPLIT)   // 512
#define BK     64
#define NSTEP  (KC / BK)         // 8
#define BM     256
#define BN     128

typedef float f32x4 __attribute__((ext_vector_type(4)));
typedef short bf16x8 __attribute__((ext_vector_type(8)));
typedef short bf16x4 __attribute__((ext_vector_type(4)));

typedef unsigned int u32;
typedef __attribute__((address_space(3))) u32 lds_u32;
typedef const __attribute__((address_space(1))) u32 gbl_u32;

// direct global->LDS, 16 B per lane; LDS dest = wave-uniform base + lane*16.
__device__ __forceinline__ void gl_lds16(const void* g, void* l) {
    __builtin_amdgcn_global_load_lds((gbl_u32*)g, (lds_u32*)l, 16, 0, 0);
}

__device__ __forceinline__ bf16x4 cvt4(float a, float b, float c, float d) {
    union { __hip_bfloat162 h[2]; bf16x4 s; } u;
    u.h[0] = __float22bfloat162_rn(float2{a, b});
    u.h[1] = __float22bfloat162_rn(float2{c, d});
    return u.s;
}

__device__ __forceinline__ f32x4 bf4_to_f32(bf16x4 s) {
    f32x4 r;
    r.x = __uint_as_float(((u32)(unsigned short)s.x) << 16);
    r.y = __uint_as_float(((u32)(unsigned short)s.y) << 16);
    r.z = __uint_as_float(((u32)(unsigned short)s.z) << 16);
    r.w = __uint_as_float(((u32)(unsigned short)s.w) << 16);
    return r;
}

// -------------------------------- copy inp -> out, zero o-cols, produce Abf -
__global__ __launch_bounds__(256) void mbd_copy_kernel(const float* __restrict__ in,
                                                       float* __restrict__ out,
                                                       short* __restrict__ Abf) {
    int row = blockIdx.y;
    int c4  = blockIdx.x * 256 + threadIdx.x;   // f32x4 index within out row
    if (c4 < 2048) {
        f32x4 v = *(const f32x4*)(in + (size_t)row * FEAT + c4 * 4);
        *(f32x4*)(out + (size_t)row * OUTW + c4 * 4) = v;
        *(bf16x4*)(Abf + (size_t)row * FEAT + c4 * 4) = cvt4(v.x, v.y, v.z, v.w);
    } else if (c4 < 2080) {
        *(f32x4*)(out + (size_t)row * OUTW + c4 * 4) = (f32x4){0.f, 0.f, 0.f, 0.f};
    }
}

// ---------------------------------------------------------------- GEMM ------
// Mt_part[kc][col][row] (bf16) = (Abf[:, kc-slice] @ T[kc-slice, :])^T.
// A: bf16 [m][k] XOR-swizzled (quad ^= m&7), staged via gl_lds16 with
//    pre-swizzled per-lane GLOBAL source (m173 pattern).
// B: f32 [k][n] linear via gl_lds16, then ONE shared transpose-cvt phase
//    per step -> bf16 [n][k] XOR-swizzled tile; frags = ds_read_b128.
// Schedule/step: stage(kt+1) | frags+MFMA(kt) | bar1 | transpose(kt+1) | bar2.
__global__ __launch_bounds__(512, 2) void mbd_gemm_kernel(const short* __restrict__ Abf,
                                                          const float* __restrict__ T,
                                                          short* __restrict__ Mt) {
    __shared__ short Als[2][BM * BK];   // 2 x 32 KB bf16 [m][k] swizzled
    __shared__ float Bfs[BK * BN];      // 32 KB f32 [k][n] linear (single buf)
    __shared__ short Bbf[2][BN * BK];   // 2 x 16 KB bf16 [n][k] swizzled

    const int tid = threadIdx.x, lane = tid & 63, l15 = lane & 15, w = tid >> 6;
    const int wm = (w & 3) * 64, wn = (w >> 2) * 64;   // wave tile 64x64

    const int kc = blockIdx.x & 15;          // XCD x hosts kc {x, x+8}: A slab L2-warm
    const int n0 = (blockIdx.x >> 4) * BN;
    const int kbase = kc * KC;

    // ---- staging descriptors (per-lane global sources, wave-uniform LDS bases)
    const short* asrc[4];  const float* bsrc[4];
    short* adst[4][2];     float* bdst[4];
#pragma unroll
    for (int u = 0; u < 4; ++u) {
        const int g = w * 4 + u;                        // 1-KB chunk group 0..31
        // A: chunk g covers m = g*8+(lane>>3), quad kq' = lane&7; source quad
        // kq = kq' ^ (m&7) bakes the XOR swizzle into the linear DMA.
        const int am = g * 8 + (lane >> 3);
        const int akq = (lane & 7) ^ (lane >> 3);
        asrc[u] = Abf + (size_t)am * FEAT + kbase + akq * 8;
        adst[u][0] = &Als[0][g * 512];
        adst[u][1] = &Als[1][g * 512];
        // B: chunk g covers k-rows 2g+(lane>>5), 16-B piece lane&31 (linear)
        const int krow = g * 2 + (lane >> 5);
        bsrc[u] = T + (size_t)(kbase + krow) * NOUT + n0 + (lane & 31) * 4;
        bdst[u] = &Bfs[g * 256];
    }

    // ---- fragment LDS offsets (short units): row*64 + (quad ^ (row&7))*8
    int aro[2][4], bro[2][4];
#pragma unroll
    for (int h = 0; h < 2; ++h) {
#pragma unroll
        for (int m = 0; m < 4; ++m) {
            int row = wm + m * 16 + l15;
            aro[h][m] = row * 64 + ((((h << 2) | (lane >> 4)) ^ (l15 & 7)) * 8);
        }
#pragma unroll
        for (int n = 0; n < 4; ++n) {
            int row = wn + n * 16 + l15;
            bro[h][n] = row * 64 + ((((h << 2) | (lane >> 4)) ^ (l15 & 7)) * 8);
        }
    }

    // ---- transpose-phase constants: thread owns column tn, k-range th*16..+15
    const int tn = tid & 127, th = tid >> 7;
    const int two0 = tn * 64 + (((th * 2 + 0) ^ (tn & 7)) * 8);
    const int two1 = tn * 64 + (((th * 2 + 1) ^ (tn & 7)) * 8);

    f32x4 acc[4][4];
#pragma unroll
    for (int m = 0; m < 4; ++m)
#pragma unroll
        for (int n = 0; n < 4; ++n) acc[m][n] = (f32x4){0.f, 0.f, 0.f, 0.f};

    // ---- prologue: stage tile 0, transpose it
#pragma unroll
    for (int u = 0; u < 4; ++u) gl_lds16(asrc[u], adst[u][0]);
#pragma unroll
    for (int u = 0; u < 4; ++u) gl_lds16(bsrc[u], bdst[u]);
    __syncthreads();                       // drains DMA
    {
        float v[16];
#pragma unroll
        for (int j = 0; j < 16; ++j) v[j] = Bfs[(th * 16 + j) * BN + tn];
        bf16x8 q0, q1;
#pragma unroll
        for (int j = 0; j < 2; ++j) {
            bf16x4 lo = cvt4(v[j*8+0], v[j*8+1], v[j*8+2], v[j*8+3]);
            bf16x4 hi = cvt4(v[j*8+4], v[j*8+5], v[j*8+6], v[j*8+7]);
            bf16x8 t; t[0]=lo.x; t[1]=lo.y; t[2]=lo.z; t[3]=lo.w;
                      t[4]=hi.x; t[5]=hi.y; t[6]=hi.z; t[7]=hi.w;
            if (j == 0) q0 = t; else q1 = t;
        }
        *(bf16x8*)&Bbf[0][two0] = q0;
        *(bf16x8*)&Bbf[0][two1] = q1;
    }
    __syncthreads();

    for (int kt = 0; kt < NSTEP; ++kt) {
        const int cur = kt & 1, nxt = cur ^ 1;
        // phase 1: fire-and-forget stage of tile kt+1 (A -> Als[nxt], B -> Bfs)
        if (kt + 1 < NSTEP) {
#pragma unroll
            for (int u = 0; u < 4; ++u)
                gl_lds16(asrc[u] + (kt + 1) * BK, adst[u][nxt]);
#pragma unroll
            for (int u = 0; u < 4; ++u)
                gl_lds16(bsrc[u] + (size_t)(kt + 1) * BK * NOUT, bdst[u]);
        }
        // phase 2: fragments + MFMA on tile kt
        bf16x8 af[2][4], bf[2][4];
#pragma unroll
        for (int h = 0; h < 2; ++h) {
#pragma unroll
            for (int m = 0; m < 4; ++m) af[h][m] = *(const bf16x8*)&Als[cur][aro[h][m]];
#pragma unroll
            for (int n = 0; n < 4; ++n) bf[h][n] = *(const bf16x8*)&Bbf[cur][bro[h][n]];
        }
        __builtin_amdgcn_s_setprio(1);
#pragma unroll
        for (int h = 0; h < 2; ++h)
#pragma unroll
            for (int m = 0; m < 4; ++m)
#pragma unroll
                for (int n = 0; n < 4; ++n)
                    acc[m][n] = __builtin_amdgcn_mfma_f32_16x16x32_bf16(
                        af[h][m], bf[h][n], acc[m][n], 0, 0, 0);
        __builtin_amdgcn_s_setprio(0);
        __syncthreads();   // bar1: staged tile kt+1 landed (drain hidden under MFMA)
        // phase 3: shared transpose-cvt of tile kt+1 (Bfs -> Bbf[nxt])
        if (kt + 1 < NSTEP) {
            float v[16];
#pragma unroll
            for (int j = 0; j < 16; ++j) v[j] = Bfs[(th * 16 + j) * BN + tn];
            bf16x8 q0, q1;
#pragma unroll
            for (int j = 0; j < 2; ++j) {
                bf16x4 lo = cvt4(v[j*8+0], v[j*8+1], v[j*8+2], v[j*8+3]);
                bf16x4 hi = cvt4(v[j*8+4], v[j*8+5], v[j*8+6], v[j*8+7]);
                bf16x8 t; t[0]=lo.x; t[1]=lo.y; t[2]=lo.z; t[3]=lo.w;
                          t[4]=hi.x; t[5]=hi.y; t[6]=hi.z; t[7]=hi.w;
                if (j == 0) q0 = t; else q1 = t;
            }
            *(bf16x8*)&Bbf[nxt][two0] = q0;
            *(bf16x8*)&Bbf[nxt][two1] = q1;
        }
        __syncthreads();   // bar2: Bbf[nxt] visible; Bfs free for next stage
    }

    // epilogue: C/D layout col = l&15, row = (l>>4)*4 + r  [m89-verified]
    short* Mp = Mt + (size_t)kc * NOUT * NS;
    const int r0 = (lane >> 4) * 4;
#pragma unroll
    for (int m = 0; m < 4; ++m)
#pragma unroll
        for (int n = 0; n < 4; ++n) {
            int col = n0 + wn + n * 16 + l15;
            int row = wm + m * 16 + r0;
            *(bf16x4*)&Mp[(size_t)col * NS + row] =
                cvt4(acc[m][n].x, acc[m][n].y, acc[m][n].z, acc[m][n].w);
        }
}

// ---------------------------------------------------------------- pairwise --
// block (b, jhalf): o_part[i,b] = sum_{j in half} exp(-sum_c |M[i,c]-M[j,c]|)
// Mt bf16 layout [p][col][row]; fold reads fully coalesced.
__global__ __launch_bounds__(256) void mbd_pair_kernel(const short* __restrict__ Mt,
                                                       float* __restrict__ out) {
    const int b = blockIdx.x >> 1, jh = blockIdx.x & 1;
    const int t = threadIdx.x;
    __shared__ float ldsT[CD][NS];       // [c][row] 16 KB
    __shared__ float rows[NS][20];       // [row][c] padded (80 B pitch) 20 KB

#pragma unroll
    for (int u4 = 0; u4 < 4; ++u4) {
        int u = t + u4 * 256;
        int c = u >> 6, r4 = (u & 63) * 4;
        f32x4 v = (f32x4){0.f, 0.f, 0.f, 0.f};
#pragma unroll
        for (int p = 0; p < KSPLIT; ++p)
            v += bf4_to_f32(*(const bf16x4*)(Mt +
                     ((size_t)p * NOUT + (size_t)b * CD + c) * NS + r4));
        *(f32x4*)&ldsT[c][r4] = v;
    }
    __syncthreads();

    float my[16];
#pragma unroll
    for (int c = 0; c < 16; ++c) my[c] = ldsT[c][t];   // contiguous -> conflict-free
#pragma unroll
    for (int c = 0; c < 16; ++c) rows[t][c] = my[c];
    __syncthreads();

    float o0 = 0.f, o1 = 0.f;
    const int jbase = jh * 128;
    for (int jj = 0; jj < 128; jj += 2) {
#pragma unroll
        for (int s = 0; s < 2; ++s) {
            const float* rp = &rows[jbase + jj + s][0];   // uniform -> broadcast
            float d0 = 0.f, d1 = 0.f, d2 = 0.f, d3 = 0.f;
#pragma unroll
            for (int q = 0; q < 4; ++q) {
                f32x4 r = *(const f32x4*)(rp + q * 4);
                d0 += fabsf(my[q * 4 + 0] - r.x);
                d1 += fabsf(my[q * 4 + 1] - r.y);
                d2 += fabsf(my[q * 4 + 2] - r.z);
                d3 += fabsf(my[q * 4 + 3] - r.w);
            }
            float d = (d0 + d1) + (d2 + d3);
            if (s == 0) o0 += __expf(-d); else o1 += __expf(-d);
        }
    }
    // exactly two addends per address -> f32 add commutative -> deterministic
    atomicAdd(&out[(size_t)t * OUTW + FEAT + b], o0 + o1);
}

// ---------------------------------------------------------------- launch ----
extern "C" void kernel_launch(void* const* d_in, const int* in_sizes, int n_in,
                              void* d_out, int out_size, void* d_ws, size_t ws_size,
                              hipStream_t stream) {
    const float* inp = (const float*)d_in[0];
    const float* T   = (const float*)d_in[1];
    float* out = (float*)d_out;

    // ws layout: Abf bf16 [256][8192] = 4 MiB, then Mt bf16 [16][2048][256] = 16 MiB.
    short* Abf = (short*)d_ws;
    short* Mt  = Abf + (size_t)NS * FEAT;

    mbd_copy_kernel<<<dim3(9, 256), 256, 0, stream>>>(inp, out, Abf);
    mbd_gemm_kernel<<<256, 512, 0, stream>>>(Abf, T, Mt);
    mbd_pair_kernel<<<BD * 2, 256, 0, stream>>>(Mt, out);
}